// Round 2
// baseline (58.527 us; speedup 1.0000x reference)
//
#include <hip/hip_runtime.h>

namespace {
constexpr int B_ = 32, S_ = 8, T_ = 128, D_ = 768, A_ = 8, L_ = 8;
constexpr int BS = B_ * S_;                 // 256
constexpr int MEAN_ELEMS = BS * D_;         // 196608
constexpr int EXT_ELEMS  = BS * A_ * D_;    // 1572864
constexpr int NO   = 3 * A_;                // 24 weighted outputs per (b,s)
constexpr int NTOK = NO * L_;               // 192 tokens per (b,s)
constexpr int NTHR = 384;                   // each thread owns 2 cols (float2)

__global__ void __launch_bounds__(NTHR, 1) srl_fused(
    const float* __restrict__ emb,
    const int* __restrict__ sids,
    const int* __restrict__ pred,
    const int* __restrict__ arg0,
    const int* __restrict__ arg1,
    float* __restrict__ out)
{
    const int bs  = blockIdx.x;
    const int tid = threadIdx.x;

    __shared__ int toks[NTOK];
    __shared__ unsigned cnt[NO][T_];                         // match multiplicity
    __shared__ __attribute__((aligned(16))) unsigned packed[T_][8]; // bytes: o=4j+k
    __shared__ float invs[NO];

    // ---- 1. load all 192 token ids; zero cnt ----
    if (tid < NTOK) {
        int e = tid >> 6;
        const int* p = (e == 0) ? pred : ((e == 1) ? arg0 : arg1);
        toks[tid] = p[(size_t)bs * 64 + (tid & 63)];
    }
    for (int i = tid; i < NO * T_; i += NTHR) ((unsigned*)cnt)[i] = 0u;
    __syncthreads();

    // ---- 2. thread t scans tokens for matches with its sentence id;
    //         a spare wave computes 1/n_valid per output ----
    if (tid < T_) {
        int id = sids[(size_t)bs * T_ + tid];
        if (id != 0) {
            for (int i = 0; i < NTOK; ++i)
                if (toks[i] == id) atomicAdd(&cnt[i >> 3][tid], 1u);
        }
    } else if (tid >= 320 && tid < 320 + NO) {
        int o = tid - 320, n = 0;
        #pragma unroll
        for (int l = 0; l < L_; ++l) n += (toks[o * L_ + l] != 0);
        invs[o] = 1.0f / (float)(n < 1 ? 1 : n);
    }
    __syncthreads();

    // ---- 3. pack weights: packed[t][j] = counts for outputs 4j..4j+3 ----
    if (tid < T_) {
        #pragma unroll
        for (int j = 0; j < 6; ++j) {
            unsigned v = 0;
            #pragma unroll
            for (int k = 0; k < 4; ++k) v |= (cnt[j * 4 + k][tid] & 255u) << (8 * k);
            packed[tid][j] = v;
        }
        packed[tid][6] = 0u;
        packed[tid][7] = 0u;
    }
    __syncthreads();

    // ---- 4. stream the [T][D] slice once; accumulate mean + 24 weighted sums ----
    const float2* eb = reinterpret_cast<const float2*>(emb + (size_t)bs * T_ * D_);
    float2 accm = {0.f, 0.f};
    float2 acc[NO];
    #pragma unroll
    for (int o = 0; o < NO; ++o) acc[o] = {0.f, 0.f};

    float2 Abuf[8], Bbuf[8];
    #pragma unroll
    for (int k = 0; k < 8; ++k) Abuf[k] = eb[(size_t)k * (D_ / 2) + tid];

    auto proc = [&](const float2* buf, int tbase) {
        #pragma unroll
        for (int k = 0; k < 8; ++k) {
            int t = tbase + k;
            float2 v = buf[k];
            accm.x += v.x; accm.y += v.y;
            uint4 w0 = *reinterpret_cast<const uint4*>(&packed[t][0]);
            uint2 w1 = *reinterpret_cast<const uint2*>(&packed[t][4]);
            unsigned ws[6] = {w0.x, w0.y, w0.z, w0.w, w1.x, w1.y};
            #pragma unroll
            for (int j = 0; j < 6; ++j) {
                unsigned wj = __builtin_amdgcn_readfirstlane(ws[j]);
                if (wj) {
                    #pragma unroll
                    for (int kb = 0; kb < 4; ++kb) {
                        unsigned c = (wj >> (8 * kb)) & 255u;
                        if (c) {
                            float fc = (float)c;
                            acc[j * 4 + kb].x += fc * v.x;
                            acc[j * 4 + kb].y += fc * v.y;
                        }
                    }
                }
            }
        }
    };

    for (int t0 = 0; t0 < T_; t0 += 16) {
        #pragma unroll
        for (int k = 0; k < 8; ++k) Bbuf[k] = eb[(size_t)(t0 + 8 + k) * (D_ / 2) + tid];
        proc(Abuf, t0);
        if (t0 + 16 < T_) {
            #pragma unroll
            for (int k = 0; k < 8; ++k) Abuf[k] = eb[(size_t)(t0 + 16 + k) * (D_ / 2) + tid];
        }
        proc(Bbuf, t0 + 8);
    }

    // ---- 5. scale + store (all float2, coalesced) ----
    reinterpret_cast<float2*>(out)[(size_t)bs * (D_ / 2) + tid] =
        {accm.x * (1.0f / T_), accm.y * (1.0f / T_)};
    #pragma unroll
    for (int o = 0; o < NO; ++o) {
        int e = o >> 3, a = o & 7;
        float iv = invs[o];
        float2* po = reinterpret_cast<float2*>(
            out + MEAN_ELEMS + (size_t)e * EXT_ELEMS + (size_t)(bs * A_ + a) * D_);
        po[tid] = {acc[o].x * iv, acc[o].y * iv};
    }
}
} // namespace

extern "C" void kernel_launch(void* const* d_in, const int* in_sizes, int n_in,
                              void* d_out, int out_size, void* d_ws, size_t ws_size,
                              hipStream_t stream) {
    const float* emb  = (const float*)d_in[0];
    const int*   sids = (const int*)d_in[1];
    const int*   pred = (const int*)d_in[2];
    const int*   arg0 = (const int*)d_in[3];
    const int*   arg1 = (const int*)d_in[4];
    float* out = (float*)d_out;

    srl_fused<<<dim3(BS), dim3(NTHR), 0, stream>>>(emb, sids, pred, arg0, arg1, out);
}

// Round 3
// 45.654 us; speedup vs baseline: 1.2820x; 1.2820x over previous
//
#include <hip/hip_runtime.h>

namespace {
constexpr int B_ = 32, S_ = 8, T_ = 128, D_ = 768, A_ = 8, L_ = 8;
constexpr int BS = B_ * S_;                 // 256
constexpr int MEAN_ELEMS = BS * D_;         // 196608
constexpr int EXT_ELEMS  = BS * A_ * D_;    // 1572864
constexpr int TSPLIT = 4, TCH = T_ / TSPLIT;
constexpr int D4 = D_ / 4;                  // 192 float4 per row
constexpr int RED_BLOCKS = BS * D4 / 256;   // 192
constexpr int EXT_BLOCKS = BS * A_;         // 2048
constexpr size_t WS_FLOATS = (size_t)TSPLIT * BS * D_;   // 3 MB

// ---- mean partial sums: block (bs, chunk), thread owns one float4 column ----
__global__ void __launch_bounds__(192) k_mean_partial(
    const float* __restrict__ emb, float* __restrict__ ws)
{
    int blk = blockIdx.x;
    int bs = blk >> 2, ch = blk & 3;
    int tid = threadIdx.x;
    const float4* p = reinterpret_cast<const float4*>(emb + (size_t)bs * T_ * D_)
                      + (size_t)(ch * TCH) * D4 + tid;
    float4 acc = {0.f, 0.f, 0.f, 0.f};
    #pragma unroll 8
    for (int t = 0; t < TCH; ++t) {
        float4 v = p[(size_t)t * D4];
        acc.x += v.x; acc.y += v.y; acc.z += v.z; acc.w += v.w;
    }
    reinterpret_cast<float4*>(ws)[(size_t)(ch * BS + bs) * D4 + tid] = acc;
}

// ---- fallback: full mean directly to out (no ws) ----
__global__ void __launch_bounds__(192) k_mean_full(
    const float* __restrict__ emb, float* __restrict__ out)
{
    int bs = blockIdx.x, tid = threadIdx.x;
    const float4* p = reinterpret_cast<const float4*>(emb + (size_t)bs * T_ * D_) + tid;
    float4 acc = {0.f, 0.f, 0.f, 0.f};
    #pragma unroll 8
    for (int t = 0; t < T_; ++t) {
        float4 v = p[(size_t)t * D4];
        acc.x += v.x; acc.y += v.y; acc.z += v.z; acc.w += v.w;
    }
    const float s = 1.0f / T_;
    float4 r = {acc.x * s, acc.y * s, acc.z * s, acc.w * s};
    reinterpret_cast<float4*>(out)[(size_t)bs * D4 + tid] = r;
}

// ---- tail: first RED blocks reduce ws -> mean out; rest do merged extract ----
template <bool WITH_RED>
__global__ void __launch_bounds__(256) k_tail(
    const float* __restrict__ emb,
    const int* __restrict__ sids,
    const int* __restrict__ pred,
    const int* __restrict__ arg0,
    const int* __restrict__ arg1,
    const float* __restrict__ ws,
    float* __restrict__ out)
{
    int blk = blockIdx.x;
    int tid = threadIdx.x;

    if (WITH_RED) {
        if (blk < RED_BLOCKS) {
            int idx = blk * 256 + tid;                    // [0, BS*D4)
            const float4* w = reinterpret_cast<const float4*>(ws);
            float4 a = w[idx];
            float4 b = w[(size_t)BS * D4 + idx];
            float4 c = w[2 * (size_t)BS * D4 + idx];
            float4 d = w[3 * (size_t)BS * D4 + idx];
            const float s = 1.0f / T_;
            float4 r = {(a.x + b.x + c.x + d.x) * s, (a.y + b.y + c.y + d.y) * s,
                        (a.z + b.z + c.z + d.z) * s, (a.w + b.w + c.w + d.w) * s};
            reinterpret_cast<float4*>(out)[idx] = r;
            return;
        }
        blk -= RED_BLOCKS;
    }

    // merged extract: one block per (bs, a), all 3 extracts
    int bs = blk >> 3, a = blk & 7;
    constexpr int NT = 3 * L_;                            // 24 tokens
    __shared__ int toks[NT];
    __shared__ int pos[NT];
    __shared__ float invs[3];

    if (tid < NT) {
        int e = tid >> 3, l = tid & 7;
        const int* p = (e == 0) ? pred : ((e == 1) ? arg0 : arg1);
        toks[tid] = p[(size_t)(bs * A_ + a) * L_ + l];
        pos[tid] = -1;
    }
    __syncthreads();
    if (tid < T_) {
        int id = sids[(size_t)bs * T_ + tid];
        #pragma unroll
        for (int i = 0; i < NT; ++i)
            if (toks[i] != 0 && toks[i] == id) pos[i] = tid;  // ids unique
    } else if (tid >= 128 && tid < 128 + 3) {
        int e = tid - 128, n = 0;
        #pragma unroll
        for (int l = 0; l < L_; ++l) n += (toks[e * L_ + l] != 0);
        invs[e] = 1.0f / (float)(n < 1 ? 1 : n);
    }
    __syncthreads();

    const float* base = emb + (size_t)bs * T_ * D_;
    float acc[3][3] = {};
    #pragma unroll
    for (int e = 0; e < 3; ++e) {
        #pragma unroll
        for (int l = 0; l < L_; ++l) {
            int p = pos[e * L_ + l];
            if (p >= 0) {
                const float* row = base + (size_t)p * D_;
                acc[e][0] += row[tid];
                acc[e][1] += row[tid + 256];
                acc[e][2] += row[tid + 512];
            }
        }
    }
    #pragma unroll
    for (int e = 0; e < 3; ++e) {
        float iv = invs[e];
        float* o = out + MEAN_ELEMS + (size_t)e * EXT_ELEMS + (size_t)(bs * A_ + a) * D_;
        o[tid]       = acc[e][0] * iv;
        o[tid + 256] = acc[e][1] * iv;
        o[tid + 512] = acc[e][2] * iv;
    }
}
} // namespace

extern "C" void kernel_launch(void* const* d_in, const int* in_sizes, int n_in,
                              void* d_out, int out_size, void* d_ws, size_t ws_size,
                              hipStream_t stream) {
    const float* emb  = (const float*)d_in[0];
    const int*   sids = (const int*)d_in[1];
    const int*   pred = (const int*)d_in[2];
    const int*   arg0 = (const int*)d_in[3];
    const int*   arg1 = (const int*)d_in[4];
    float* out = (float*)d_out;
    float* ws  = (float*)d_ws;

    if (ws_size >= WS_FLOATS * sizeof(float)) {
        k_mean_partial<<<dim3(BS * TSPLIT), dim3(192), 0, stream>>>(emb, ws);
        k_tail<true><<<dim3(RED_BLOCKS + EXT_BLOCKS), dim3(256), 0, stream>>>(
            emb, sids, pred, arg0, arg1, ws, out);
    } else {
        k_mean_full<<<dim3(BS), dim3(192), 0, stream>>>(emb, out);
        k_tail<false><<<dim3(EXT_BLOCKS), dim3(256), 0, stream>>>(
            emb, sids, pred, arg0, arg1, ws, out);
    }
}

// Round 4
// 43.853 us; speedup vs baseline: 1.3346x; 1.0411x over previous
//
#include <hip/hip_runtime.h>

namespace {
constexpr int B_ = 32, S_ = 8, T_ = 128, D_ = 768, A_ = 8, L_ = 8;
constexpr int BS = B_ * S_;                 // 256
constexpr int MEAN_ELEMS = BS * D_;         // 196608
constexpr int EXT_ELEMS  = BS * A_ * D_;    // 1572864
constexpr int D4 = D_ / 4;                  // 192 float4 per row
constexpr int MEAN_BLOCKS = BS;             // 256 (one per bs)
constexpr int EXT_BLOCKS  = BS * A_;        // 2048 (one per bs,a — all 3 extracts)

// Heterogeneous single dispatch:
//   blocks [0, 256)     : mean over T for one (b,s)   — BW-bound stream
//   blocks [256, 2304)  : extract for one (b,s,a)×3e  — latency-bound gather
// Extract reads the same bytes the mean streams -> L2/L3 hits; running them
// concurrently hides gather latency under the HBM stream.
__global__ void __launch_bounds__(256) srl_one(
    const float* __restrict__ emb,
    const int* __restrict__ sids,
    const int* __restrict__ pred,
    const int* __restrict__ arg0,
    const int* __restrict__ arg1,
    float* __restrict__ out)
{
    const int blk = blockIdx.x;
    const int tid = threadIdx.x;

    if (blk < MEAN_BLOCKS) {
        // ---- mean: 192 threads, one float4 column each, serial over T ----
        if (tid >= 192) return;
        const int bs = blk;
        const float4* p = reinterpret_cast<const float4*>(emb + (size_t)bs * T_ * D_) + tid;
        float4 acc = {0.f, 0.f, 0.f, 0.f};
        #pragma unroll 8
        for (int t = 0; t < T_; ++t) {
            float4 v = p[(size_t)t * D4];
            acc.x += v.x; acc.y += v.y; acc.z += v.z; acc.w += v.w;
        }
        const float s = 1.0f / T_;
        float4 r = {acc.x * s, acc.y * s, acc.z * s, acc.w * s};
        reinterpret_cast<float4*>(out)[(size_t)bs * D4 + tid] = r;
        return;
    }

    // ---- extract: one block per (bs, a), all 3 extracts ----
    const int eblk = blk - MEAN_BLOCKS;
    const int bs = eblk >> 3, a = eblk & 7;
    constexpr int NT = 3 * L_;                            // 24 tokens
    __shared__ int toks[NT];
    __shared__ int pos[NT];
    __shared__ float invs[3];

    if (tid < NT) {
        int e = tid >> 3, l = tid & 7;
        const int* p = (e == 0) ? pred : ((e == 1) ? arg0 : arg1);
        toks[tid] = p[(size_t)(bs * A_ + a) * L_ + l];
        pos[tid] = -1;
    }
    __syncthreads();
    if (tid < T_) {
        int id = sids[(size_t)bs * T_ + tid];
        #pragma unroll
        for (int i = 0; i < NT; ++i)
            if (toks[i] != 0 && toks[i] == id) pos[i] = tid;  // ids unique per sentence
    } else if (tid >= 128 && tid < 128 + 3) {
        int e = tid - 128, n = 0;
        #pragma unroll
        for (int l = 0; l < L_; ++l) n += (toks[e * L_ + l] != 0);
        invs[e] = 1.0f / (float)(n < 1 ? 1 : n);
    }
    __syncthreads();

    const float* base = emb + (size_t)bs * T_ * D_;
    float acc[3][3] = {};
    #pragma unroll
    for (int e = 0; e < 3; ++e) {
        #pragma unroll
        for (int l = 0; l < L_; ++l) {
            int p = pos[e * L_ + l];
            if (p >= 0) {
                const float* row = base + (size_t)p * D_;
                acc[e][0] += row[tid];
                acc[e][1] += row[tid + 256];
                acc[e][2] += row[tid + 512];
            }
        }
    }
    #pragma unroll
    for (int e = 0; e < 3; ++e) {
        float iv = invs[e];
        float* o = out + MEAN_ELEMS + (size_t)e * EXT_ELEMS + (size_t)(bs * A_ + a) * D_;
        o[tid]       = acc[e][0] * iv;
        o[tid + 256] = acc[e][1] * iv;
        o[tid + 512] = acc[e][2] * iv;
    }
}
} // namespace

extern "C" void kernel_launch(void* const* d_in, const int* in_sizes, int n_in,
                              void* d_out, int out_size, void* d_ws, size_t ws_size,
                              hipStream_t stream) {
    const float* emb  = (const float*)d_in[0];
    const int*   sids = (const int*)d_in[1];
    const int*   pred = (const int*)d_in[2];
    const int*   arg0 = (const int*)d_in[3];
    const int*   arg1 = (const int*)d_in[4];
    float* out = (float*)d_out;

    srl_one<<<dim3(MEAN_BLOCKS + EXT_BLOCKS), dim3(256), 0, stream>>>(
        emb, sids, pred, arg0, arg1, out);
}